// Round 7
// baseline (415.392 us; speedup 1.0000x reference)
//
#include <hip/hip_runtime.h>
#include <math.h>

#define NNODES 50000
#define NEDGES 800000
#define NBUCK  256          // buckets = dst >> 8 ; used: ceil(50000/256) = 196
#define NBUCK_USED ((NNODES + 255) >> 8)
#define CAP    6144         // max edges per bucket (mean 4352, sd ~66)
#define PB_EDGES 4096       // edges per bin_edges block

typedef __attribute__((ext_vector_type(8))) short short8v;
typedef __attribute__((ext_vector_type(4))) float f32x4;
typedef unsigned short ushort;

static __device__ __forceinline__ ushort f2bf(float f){
  union { float f; unsigned u; } v; v.f = f;
  unsigned r = (v.u + 0x7fffu + ((v.u >> 16) & 1u)) >> 16;   // RNE
  return (ushort)r;
}
static __device__ __forceinline__ float bflo(unsigned hv){
  union { unsigned u; float f; } v; v.u = hv << 16; return v.f;
}
static __device__ __forceinline__ float bfhi(unsigned hv){
  union { unsigned u; float f; } v; v.u = hv & 0xffff0000u; return v.f;
}

// ---------------- CSR build: two-level LDS-staged counting sort ----------------

__global__ __launch_bounds__(256) void bin_edges_kernel(
    const int* __restrict__ ei, int* __restrict__ cursor_b,
    uint2* __restrict__ binned, int E, int n){
  __shared__ int lcnt[NBUCK];
  __shared__ int lofs[NBUCK];
  __shared__ int gbase[NBUCK];
  __shared__ int sc[NBUCK];
  __shared__ uint2 stage[PB_EDGES];          // 32 KB
  const int tid = threadIdx.x;
  const int base = blockIdx.x * PB_EDGES;
  const int tot = E + n;
  const int cnt = min(PB_EDGES, tot - base);

  lcnt[tid] = 0;
  __syncthreads();

  uint2 ed[PB_EDGES/256];
  #pragma unroll
  for (int k = 0; k < PB_EDGES/256; k++){
    int idx = base + tid + k*256;            // coalesced
    if (idx < tot){
      int s, d;
      if (idx < E){ s = ei[idx]; d = ei[E+idx]; } else { s = idx - E; d = s; }
      ed[k].x = (unsigned)s; ed[k].y = (unsigned)d;
      atomicAdd(&lcnt[d >> 8], 1);
    }
  }
  __syncthreads();

  sc[tid] = lcnt[tid];
  __syncthreads();
  for (int off = 1; off < NBUCK; off <<= 1){
    int t = (tid >= off) ? sc[tid - off] : 0;
    __syncthreads();
    sc[tid] += t;
    __syncthreads();
  }
  lofs[tid] = sc[tid] - lcnt[tid];
  gbase[tid] = atomicAdd(&cursor_b[tid], lcnt[tid]);
  __syncthreads();
  lcnt[tid] = 0;                             // reuse as rank counters
  __syncthreads();

  #pragma unroll
  for (int k = 0; k < PB_EDGES/256; k++){
    int idx = base + tid + k*256;
    if (idx < tot){
      int b = ed[k].y >> 8;
      int r = atomicAdd(&lcnt[b], 1);
      stage[lofs[b] + r] = ed[k];
    }
  }
  __syncthreads();

  for (int idx = tid; idx < cnt; idx += 256){
    uint2 p = stage[idx];
    int b = p.y >> 8;
    binned[(size_t)b*CAP + gbase[b] + (idx - lofs[b])] = p;
  }
}

// per-bucket counting sort by dst -> csr_src (coalesced) + rowptr.
__global__ __launch_bounds__(256) void build_csr_kernel(
    const uint2* __restrict__ binned, const int* __restrict__ cursor_b,
    int* __restrict__ csr_src, int* __restrict__ rowptr, int n, int tot){
  __shared__ int bc[256];
  __shared__ int sc[256];
  __shared__ int cnt256[256];
  __shared__ int ofs[256];
  __shared__ int stage[CAP];                 // 24 KB
  const int b = blockIdx.x;
  const int tid = threadIdx.x;

  int c = cursor_b[tid];
  bc[tid] = c; sc[tid] = c;
  __syncthreads();
  for (int off = 1; off < 256; off <<= 1){
    int t = (tid >= off) ? sc[tid - off] : 0;
    __syncthreads();
    sc[tid] += t;
    __syncthreads();
  }
  const int base = sc[b] - bc[b];
  const int cnt = min(bc[b], CAP);

  cnt256[tid] = 0;
  __syncthreads();
  for (int i = tid; i < cnt; i += 256){
    int d = binned[(size_t)b*CAP + i].y & 255;
    atomicAdd(&cnt256[d], 1);
  }
  __syncthreads();
  sc[tid] = cnt256[tid];
  __syncthreads();
  for (int off = 1; off < 256; off <<= 1){
    int t = (tid >= off) ? sc[tid - off] : 0;
    __syncthreads();
    sc[tid] += t;
    __syncthreads();
  }
  ofs[tid] = sc[tid] - cnt256[tid];
  __syncthreads();
  cnt256[tid] = 0;
  __syncthreads();
  for (int i = tid; i < cnt; i += 256){
    uint2 p = binned[(size_t)b*CAP + i];
    int d = p.y & 255;
    int r = atomicAdd(&cnt256[d], 1);
    stage[ofs[d] + r] = (int)p.x;
  }
  __syncthreads();
  for (int i = tid; i < cnt; i += 256)
    csr_src[base + i] = stage[i];
  int node = b*256 + tid;
  if (node < n) rowptr[node] = base + ofs[tid];
  if (b == 0 && tid == 0) rowptr[n] = tot;
}

// ---------------- one prep kernel: x-convert+alpha1 | weight transposes | vecs | zeroing ----------------
// grid layout: [0,12500) x-prep | [12500,12884) weights | 12884 vecs | [12885,12885+98) zero

#define PREP_XB 12500
#define PREP_WB 384
#define PREP_ZB 98

__global__ __launch_bounds__(256) void prep_all_kernel(
    const float* __restrict__ x, const float* __restrict__ W1, const float* __restrict__ W2,
    const float* __restrict__ Wm1, const float* __restrict__ Wm2,
    const float* __restrict__ a1s, const float* __restrict__ a1d,
    const float* __restrict__ a2s, const float* __restrict__ a2d,
    ushort* __restrict__ xb, float* __restrict__ as1, float* __restrict__ ad1,
    ushort* __restrict__ W1t, ushort* __restrict__ W2t,
    ushort* __restrict__ Wm1t, ushort* __restrict__ Wm2t,
    float* __restrict__ u1, float* __restrict__ v1,
    float* __restrict__ u2, float* __restrict__ v2,
    uint4* __restrict__ zero_base, int n){
  const int b = blockIdx.x;
  const int tid = threadIdx.x;
  if (b < PREP_XB){
    int gid = b*256 + tid;
    int node = gid >> 6, lane = gid & 63;
    if (node >= n) return;
    float xv = x[(size_t)node*64 + lane];
    xb[(size_t)node*64 + lane] = f2bf(xv);
    float ps = xv * u1[lane], pd = xv * v1[lane];   // u1/v1 written by vecs part of a PREVIOUS call? NO —
    // u1/v1 are produced in this same kernel by another block: NOT ordered! compute alphas directly instead.
    (void)ps; (void)pd;
    // recompute per-lane dot contributions with a1s/a1d folded through W1 row:
    // as1[node] = sum_c (x W1)[c] a1s[c] = x . (W1 a1s) ; do the 128-dot per lane here:
    float su = 0.f, sv = 0.f;
    const float* wrow = W1 + (size_t)lane*128;
    #pragma unroll 4
    for (int c = 0; c < 128; c++){ float w = wrow[c]; su += w*a1s[c]; sv += w*a1d[c]; }
    ps = xv * su; pd = xv * sv;
    #pragma unroll
    for (int off = 32; off; off >>= 1){
      ps += __shfl_xor(ps, off);
      pd += __shfl_xor(pd, off);
    }
    if (lane == 0){ as1[node] = ps; ad1[node] = pd; }
    return;
  }
  if (b < PREP_XB + PREP_WB){
    int i = (b - PREP_XB)*256 + tid;
    if (i < 8192){                              // W1t[n][k], N=128, K=64
      int n_ = i >> 6, k_ = i & 63;
      W1t[i] = f2bf(W1[(size_t)k_*128 + n_]);
    } else if (i < 16384){                      // W2t[n][k], N=64, K=128
      int j = i - 8192;
      int n_ = j >> 7, k_ = j & 127;
      W2t[j] = f2bf(W2[(size_t)k_*64 + n_]);
    } else if (i < 32768){                      // Wm1t[n][k], N=256, K=64
      int j = i - 16384;
      int n_ = j >> 6, k_ = j & 63;
      Wm1t[j] = f2bf(Wm1[(size_t)k_*256 + n_]);
    } else {                                    // Wm2t[n][k], N=256, K=256
      int j = i - 32768;
      int n_ = j >> 8, k_ = j & 255;
      Wm2t[j] = f2bf(Wm2[(size_t)k_*256 + n_]);
    }
    return;
  }
  if (b == PREP_XB + PREP_WB){
    int t = tid;
    if (t < 128){                               // u2/v2 = W2 @ a2s / a2d (needed by ALPHA gemm)
      float su = 0.f, sv = 0.f;
      for (int c = 0; c < 64; c++){ float w = W2[(size_t)t*64 + c]; su += w*a2s[c]; sv += w*a2d[c]; }
      u2[t] = su; v2[t] = sv;
    } else if (t < 192){                        // u1/v1 kept for completeness (unused now)
      int k = t - 128;
      float su = 0.f, sv = 0.f;
      for (int c = 0; c < 128; c++){ float w = W1[(size_t)k*128 + c]; su += w*a1s[c]; sv += w*a1d[c]; }
      u1[k] = su; v1[k] = sv;
    }
    return;
  }
  // zero blocks: 98 x 4KB = 401408 B
  int z = b - (PREP_XB + PREP_WB + 1);
  zero_base[(size_t)z*256 + tid] = (uint4){0u,0u,0u,0u};
}

// ---------------- fused GAT aggregation, C=64 ----------------
// wave per dst; chunk-of-64 softmax in lanes; (w,s) staged to LDS;
// gather: half-wave per edge (dword = 2ch/lane), unrolled 4 pairs.

template<bool BIASRELU>
__global__ __launch_bounds__(256) void aggc64_kernel(
    const int* __restrict__ rowptr, const int* __restrict__ csr_src,
    const ushort* __restrict__ h, const float* __restrict__ as,
    const float* __restrict__ ad, const float* __restrict__ bias,
    ushort* __restrict__ out, int n){
  __shared__ uint2 spair[4][72];
  int gid = blockIdx.x*blockDim.x + threadIdx.x;
  int dst = gid >> 6, lane = gid & 63;
  if (dst >= n) return;
  int wv = threadIdx.x >> 6;
  if (lane < 8) spair[wv][64 + lane] = (uint2){0u, 0u};   // zero tail once
  int r0 = rowptr[dst], r1 = rowptr[dst+1];
  float adv = ad[dst];
  const int hf = lane >> 5;
  const int ch = (lane & 31) * 2;
  float m = -INFINITY, denom = 0.f, acc0 = 0.f, acc1 = 0.f;
  for (int j0 = r0; j0 < r1; j0 += 64){
    int j = j0 + lane;
    int cnt = min(64, r1 - j0);
    bool valid = (j < r1);
    int s = valid ? csr_src[j] : 0;
    float e = -INFINITY;
    if (valid){
      e = as[s] + adv;
      e = (e > 0.f) ? e : 0.2f*e;
    }
    float cm = e;
    #pragma unroll
    for (int off = 32; off; off >>= 1) cm = fmaxf(cm, __shfl_xor(cm, off));
    float mn = fmaxf(m, cm);
    float w = valid ? __expf(e - mn) : 0.f;
    float csum = w;
    #pragma unroll
    for (int off = 32; off; off >>= 1) csum += __shfl_xor(csum, off);
    float scale = __expf(m - mn);          // first chunk: exp(-inf)=0
    denom = denom*scale + csum;
    acc0 *= scale; acc1 *= scale;
    m = mn;
    spair[wv][lane] = (uint2){__float_as_uint(w), (unsigned)s};
    for (int k = 0; k < cnt; k += 8){
      #pragma unroll
      for (int p = 0; p < 4; p++){
        uint2 pr = spair[wv][k + 2*p + hf];
        float wp = __uint_as_float(pr.x);
        unsigned hv = *(const unsigned*)(h + ((size_t)pr.y << 6) + ch);
        acc0 += wp * bflo(hv);
        acc1 += wp * bfhi(hv);
      }
    }
  }
  acc0 += __shfl_xor(acc0, 32);
  acc1 += __shfl_xor(acc1, 32);
  if (hf == 0){
    float inv = 1.f / denom;
    float o0 = acc0*inv, o1 = acc1*inv;
    if (BIASRELU){
      o0 = fmaxf(o0 + bias[ch],   0.f);
      o1 = fmaxf(o1 + bias[ch+1], 0.f);
    }
    unsigned pack = (unsigned)f2bf(o0) | ((unsigned)f2bf(o1) << 16);
    *(unsigned*)(out + ((size_t)dst << 6) + ch) = pack;
  }
}

// ---------------- bf16 MFMA GEMM, multi-N-stripe: C[M][0:NSTR*64] = A @ Bt^T ----------------
// grid (1, M/64). A streamed once; B (small, L2-resident) staged for all stripes per k-tile.

#define SWZ(row, byte_in_row) ((((row)*128) + (byte_in_row)) ^ (((row)&7) << 4))

template<int NSTR, bool BIAS, bool RELU, bool OUTBF16, bool ALPHA>
__global__ __launch_bounds__(256) void gemm_bf16_kernel(
    const ushort* __restrict__ A, const ushort* __restrict__ Bt,
    const float* __restrict__ bias, void* __restrict__ Cout,
    int M, int K, int N,
    const float* __restrict__ u2, const float* __restrict__ v2,
    float* __restrict__ as2, float* __restrict__ ad2){
  __shared__ unsigned char lds[8192 + NSTR*8192];   // As | Bs[stripes]
  const int tid = threadIdx.x;
  const int lane = tid & 63;
  const int wid = tid >> 6;
  const int wr = (wid >> 1) * 32;
  const int wc = (wid & 1) * 32;
  const int row0 = blockIdx.y * 64;

  f32x4 acc[NSTR][2][2];
  #pragma unroll
  for (int st = 0; st < NSTR; st++)
    #pragma unroll
    for (int i = 0; i < 2; i++)
      #pragma unroll
      for (int j = 0; j < 2; j++)
        acc[st][i][j] = (f32x4){0.f, 0.f, 0.f, 0.f};

  const int lrow = lane & 15;
  const int kgrp = (lane >> 4) * 16;

  for (int k0 = 0; k0 < K; k0 += 64){
    #pragma unroll
    for (int it = 0; it < 2; it++){
      int g = tid + it*256;
      int row = g >> 3, c8 = g & 7;
      int gr = row0 + row;
      uint4 v = {0u,0u,0u,0u};
      if (gr < M) v = *(const uint4*)(A + (size_t)gr*K + k0 + c8*8);
      *(uint4*)(lds + SWZ(row, c8*16)) = v;
    }
    #pragma unroll
    for (int it = 0; it < 2*NSTR; it++){
      int g = tid + it*256;
      int row = g >> 3, c8 = g & 7;                 // row = global n in [0, NSTR*64)
      uint4 v = *(const uint4*)(Bt + (size_t)row*K + k0 + c8*8);
      *(uint4*)(lds + 8192 + (row >> 6)*8192 + SWZ(row & 63, c8*16)) = v;
    }
    __syncthreads();
    #pragma unroll
    for (int kb = 0; kb < 2; kb++){
      int kbyte = kb*64 + kgrp;
      short8v a[2];
      #pragma unroll
      for (int mi = 0; mi < 2; mi++)
        a[mi] = *(const short8v*)(lds + SWZ(wr + mi*16 + lrow, kbyte));
      #pragma unroll
      for (int st = 0; st < NSTR; st++){
        short8v bfr[2];
        #pragma unroll
        for (int ni = 0; ni < 2; ni++)
          bfr[ni] = *(const short8v*)(lds + 8192 + st*8192 + SWZ(wc + ni*16 + lrow, kbyte));
        #pragma unroll
        for (int mi = 0; mi < 2; mi++)
          #pragma unroll
          for (int ni = 0; ni < 2; ni++)
            acc[st][mi][ni] = __builtin_amdgcn_mfma_f32_16x16x32_bf16(a[mi], bfr[ni], acc[st][mi][ni], 0, 0, 0);
      }
    }
    __syncthreads();
  }

  if constexpr (ALPHA){
    #pragma unroll
    for (int mi = 0; mi < 2; mi++){
      float pu[4] = {0.f,0.f,0.f,0.f}, pv[4] = {0.f,0.f,0.f,0.f};
      int rbase = row0 + wr + mi*16 + (lane >> 4)*4;
      #pragma unroll
      for (int st = 0; st < NSTR; st++){
        #pragma unroll
        for (int ni = 0; ni < 2; ni++){
          int c = st*64 + wc + ni*16 + (lane & 15);
          float bv = BIAS ? bias[c] : 0.f;
          float uc = u2[c], vc = v2[c];
          #pragma unroll
          for (int r = 0; r < 4; r++){
            float v = acc[st][mi][ni][r] + bv;
            if (RELU) v = fmaxf(v, 0.f);
            if (rbase + r < M)
              ((ushort*)Cout)[(size_t)(rbase+r)*N + c] = f2bf(v);
            pu[r] += v*uc; pv[r] += v*vc;
          }
        }
      }
      #pragma unroll
      for (int off = 8; off; off >>= 1){
        #pragma unroll
        for (int r = 0; r < 4; r++){
          pu[r] += __shfl_xor(pu[r], off);
          pv[r] += __shfl_xor(pv[r], off);
        }
      }
      if ((lane & 15) == 0){
        #pragma unroll
        for (int r = 0; r < 4; r++){
          if (rbase + r < M){
            atomicAdd(&as2[rbase+r], pu[r]);
            atomicAdd(&ad2[rbase+r], pv[r]);
          }
        }
      }
    }
  } else {
    #pragma unroll
    for (int st = 0; st < NSTR; st++){
      #pragma unroll
      for (int mi = 0; mi < 2; mi++){
        #pragma unroll
        for (int ni = 0; ni < 2; ni++){
          int c = st*64 + wc + ni*16 + (lane & 15);
          int rbase = row0 + wr + mi*16 + (lane >> 4)*4;
          float bv = BIAS ? bias[c] : 0.f;
          #pragma unroll
          for (int r = 0; r < 4; r++){
            int row = rbase + r;
            if (row >= M) continue;
            float v = acc[st][mi][ni][r] + bv;
            if (RELU) v = fmaxf(v, 0.f);
            if (OUTBF16) ((ushort*)Cout)[(size_t)row*N + c] = f2bf(v);
            else         ((float*)Cout)[(size_t)row*N + c] = v;
          }
        }
      }
    }
  }
}

// ---------------- launch ----------------

extern "C" void kernel_launch(void* const* d_in, const int* in_sizes, int n_in,
                              void* d_out, int out_size, void* d_ws, size_t ws_size,
                              hipStream_t stream){
  const float* x   = (const float*)d_in[0];
  const int*   ei  = (const int*)d_in[1];
  const float* W1  = (const float*)d_in[3];
  const float* a1s = (const float*)d_in[4];
  const float* a1d = (const float*)d_in[5];
  const float* b1  = (const float*)d_in[6];
  const float* W2  = (const float*)d_in[7];
  const float* a2s = (const float*)d_in[8];
  const float* a2d = (const float*)d_in[9];
  const float* b2  = (const float*)d_in[10];
  const float* Wm1 = (const float*)d_in[11];
  const float* bm1 = (const float*)d_in[12];
  const float* Wm2 = (const float*)d_in[13];
  const float* bm2 = (const float*)d_in[14];
  float* out = (float*)d_out;

  const int N = NNODES, E = NEDGES;
  const int TOT = E + N;

  char* w = (char*)d_ws;
  auto alloc = [&](size_t bytes)->void*{
    void* p = (void*)w;
    w += (bytes + 255) & ~(size_t)255;
    return p;
  };
  // zero region (written by prep_all zero blocks): cursor_b | as2 | ad2 = 401408 B
  int*    cursor_b = (int*)alloc(NBUCK*4);            // 1024 B
  float*  as2      = (float*)alloc((size_t)N*4);      // 200192 B padded
  float*  ad2      = (float*)alloc((size_t)N*4);      // 200192 B padded
  uint2*  binned   = (uint2*)alloc((size_t)NBUCK*CAP*8);
  int*    rowptr   = (int*)alloc((size_t)(N+1)*4);
  int*    csr_src  = (int*)alloc((size_t)TOT*4);
  ushort* xb       = (ushort*)alloc((size_t)N*64*2);
  ushort* W1t      = (ushort*)alloc((size_t)64*128*2);
  ushort* W2t      = (ushort*)alloc((size_t)128*64*2);
  ushort* Wm1t     = (ushort*)alloc((size_t)64*256*2);
  ushort* Wm2t     = (ushort*)alloc((size_t)256*256*2);
  float*  u1       = (float*)alloc(128*4);
  float*  v1       = (float*)alloc(128*4);
  float*  u2       = (float*)alloc(128*4);
  float*  v2       = (float*)alloc(128*4);
  float*  as1      = (float*)alloc((size_t)N*4);
  float*  ad1      = (float*)alloc((size_t)N*4);
  ushort* aggx     = (ushort*)alloc((size_t)N*64*2);
  ushort* out1b    = (ushort*)alloc((size_t)N*128*2);
  ushort* h2b      = (ushort*)alloc((size_t)N*64*2);
  ushort* out2b    = (ushort*)alloc((size_t)N*64*2);
  ushort* hidb     = (ushort*)alloc((size_t)N*256*2);
  (void)ws_size; (void)n_in; (void)in_sizes; (void)out_size;

  // one prep kernel: x prep | weight transposes | u2/v2 | zero cursor_b/as2/ad2
  prep_all_kernel<<<PREP_XB + PREP_WB + 1 + PREP_ZB, 256, 0, stream>>>(
      x, W1, W2, Wm1, Wm2, a1s, a1d, a2s, a2d,
      xb, as1, ad1, W1t, W2t, Wm1t, Wm2t, u1, v1, u2, v2,
      (uint4*)cursor_b, N);

  // CSR build (sorted by dst, coalesced writes)
  const int nbB = (TOT + PB_EDGES - 1) / PB_EDGES;    // 208
  bin_edges_kernel<<<nbB, 256, 0, stream>>>(ei, cursor_b, binned, E, N);
  build_csr_kernel<<<NBUCK_USED, 256, 0, stream>>>(binned, cursor_b, csr_src, rowptr, N, TOT);

  const int mb = (N + 63)/64;
  dim3 blk(256);
  const int nwave = (N*64 + 255)/256;

  // GAT layer 1: aggregate x (64ch), then W1 (+b1, relu, as2/ad2 alphas) via GEMM
  aggc64_kernel<false><<<nwave, 256, 0, stream>>>(rowptr, csr_src, xb, as1, ad1, nullptr, aggx, N);
  gemm_bf16_kernel<2,true,true,true,true><<<dim3(1, mb), blk, 0, stream>>>(
      aggx, W1t, b1, out1b, N, 64, 128, u2, v2, as2, ad2);
  // GAT layer 2: transform then aggregate
  gemm_bf16_kernel<1,false,false,true,false><<<dim3(1, mb), blk, 0, stream>>>(
      out1b, W2t, nullptr, h2b, N, 128, 64, nullptr, nullptr, nullptr, nullptr);
  aggc64_kernel<true><<<nwave, 256, 0, stream>>>(rowptr, csr_src, h2b, as2, ad2, b2, out2b, N);
  // MLP
  gemm_bf16_kernel<4,true,true ,true ,false><<<dim3(1, mb), blk, 0, stream>>>(
      out2b, Wm1t, bm1, hidb, N, 64, 256, nullptr, nullptr, nullptr, nullptr);
  gemm_bf16_kernel<4,true,false,false,false><<<dim3(1, mb), blk, 0, stream>>>(
      hidb, Wm2t, bm2, out, N, 256, 256, nullptr, nullptr, nullptr, nullptr);
}

// Round 8
// 255.317 us; speedup vs baseline: 1.6270x; 1.6270x over previous
//
#include <hip/hip_runtime.h>
#include <math.h>

#define NNODES 50000
#define NEDGES 800000
#define NBUCK  256          // buckets = dst >> 8 ; used: ceil(50000/256) = 196
#define NBUCK_USED ((NNODES + 255) >> 8)
#define CAP    6144         // max edges per bucket (mean 4352, sd ~66)
#define PB_EDGES 4096       // edges per bin_edges block

typedef __attribute__((ext_vector_type(8))) short short8v;
typedef __attribute__((ext_vector_type(4))) float f32x4;
typedef unsigned short ushort;

static __device__ __forceinline__ ushort f2bf(float f){
  union { float f; unsigned u; } v; v.f = f;
  unsigned r = (v.u + 0x7fffu + ((v.u >> 16) & 1u)) >> 16;   // RNE
  return (ushort)r;
}
static __device__ __forceinline__ float bflo(unsigned hv){
  union { unsigned u; float f; } v; v.u = hv << 16; return v.f;
}
static __device__ __forceinline__ float bfhi(unsigned hv){
  union { unsigned u; float f; } v; v.u = hv & 0xffff0000u; return v.f;
}

// ---------------- CSR build: two-level LDS-staged counting sort ----------------

__global__ __launch_bounds__(256) void bin_edges_kernel(
    const int* __restrict__ ei, int* __restrict__ cursor_b,
    uint2* __restrict__ binned, int E, int n){
  __shared__ int lcnt[NBUCK];
  __shared__ int lofs[NBUCK];
  __shared__ int gbase[NBUCK];
  __shared__ int sc[NBUCK];
  __shared__ uint2 stage[PB_EDGES];          // 32 KB
  const int tid = threadIdx.x;
  const int base = blockIdx.x * PB_EDGES;
  const int tot = E + n;
  const int cnt = min(PB_EDGES, tot - base);

  lcnt[tid] = 0;
  __syncthreads();

  uint2 ed[PB_EDGES/256];
  #pragma unroll
  for (int k = 0; k < PB_EDGES/256; k++){
    int idx = base + tid + k*256;            // coalesced
    if (idx < tot){
      int s, d;
      if (idx < E){ s = ei[idx]; d = ei[E+idx]; } else { s = idx - E; d = s; }
      ed[k].x = (unsigned)s; ed[k].y = (unsigned)d;
      atomicAdd(&lcnt[d >> 8], 1);
    }
  }
  __syncthreads();

  sc[tid] = lcnt[tid];
  __syncthreads();
  for (int off = 1; off < NBUCK; off <<= 1){
    int t = (tid >= off) ? sc[tid - off] : 0;
    __syncthreads();
    sc[tid] += t;
    __syncthreads();
  }
  lofs[tid] = sc[tid] - lcnt[tid];
  gbase[tid] = atomicAdd(&cursor_b[tid], lcnt[tid]);
  __syncthreads();
  lcnt[tid] = 0;                             // reuse as rank counters
  __syncthreads();

  #pragma unroll
  for (int k = 0; k < PB_EDGES/256; k++){
    int idx = base + tid + k*256;
    if (idx < tot){
      int b = ed[k].y >> 8;
      int r = atomicAdd(&lcnt[b], 1);
      stage[lofs[b] + r] = ed[k];
    }
  }
  __syncthreads();

  for (int idx = tid; idx < cnt; idx += 256){
    uint2 p = stage[idx];
    int b = p.y >> 8;
    binned[(size_t)b*CAP + gbase[b] + (idx - lofs[b])] = p;
  }
}

// per-bucket counting sort by dst -> csr_src (coalesced) + rowptr.
__global__ __launch_bounds__(256) void build_csr_kernel(
    const uint2* __restrict__ binned, const int* __restrict__ cursor_b,
    int* __restrict__ csr_src, int* __restrict__ rowptr, int n, int tot){
  __shared__ int bc[256];
  __shared__ int sc[256];
  __shared__ int cnt256[256];
  __shared__ int ofs[256];
  __shared__ int stage[CAP];                 // 24 KB
  const int b = blockIdx.x;
  const int tid = threadIdx.x;

  int c = cursor_b[tid];
  bc[tid] = c; sc[tid] = c;
  __syncthreads();
  for (int off = 1; off < 256; off <<= 1){
    int t = (tid >= off) ? sc[tid - off] : 0;
    __syncthreads();
    sc[tid] += t;
    __syncthreads();
  }
  const int base = sc[b] - bc[b];
  const int cnt = min(bc[b], CAP);

  cnt256[tid] = 0;
  __syncthreads();
  for (int i = tid; i < cnt; i += 256){
    int d = binned[(size_t)b*CAP + i].y & 255;
    atomicAdd(&cnt256[d], 1);
  }
  __syncthreads();
  sc[tid] = cnt256[tid];
  __syncthreads();
  for (int off = 1; off < 256; off <<= 1){
    int t = (tid >= off) ? sc[tid - off] : 0;
    __syncthreads();
    sc[tid] += t;
    __syncthreads();
  }
  ofs[tid] = sc[tid] - cnt256[tid];
  __syncthreads();
  cnt256[tid] = 0;
  __syncthreads();
  for (int i = tid; i < cnt; i += 256){
    uint2 p = binned[(size_t)b*CAP + i];
    int d = p.y & 255;
    int r = atomicAdd(&cnt256[d], 1);
    stage[ofs[d] + r] = (int)p.x;
  }
  __syncthreads();
  for (int i = tid; i < cnt; i += 256)
    csr_src[base + i] = stage[i];
  int node = b*256 + tid;
  if (node < n) rowptr[node] = base + ofs[tid];
  if (b == 0 && tid == 0) rowptr[n] = tot;
}

// ---------------- prep 1: weight transposes | folded vectors | zeroing ----------------
// grid: [0,384) weight transposes | 384 vecs | [385, 385+98) zero blocks

#define PREP_WB 384
#define PREP_ZB 98

__global__ __launch_bounds__(256) void prep_weights_kernel(
    const float* __restrict__ W1, const float* __restrict__ W2,
    const float* __restrict__ Wm1, const float* __restrict__ Wm2,
    const float* __restrict__ a1s, const float* __restrict__ a1d,
    const float* __restrict__ a2s, const float* __restrict__ a2d,
    ushort* __restrict__ W1t, ushort* __restrict__ W2t,
    ushort* __restrict__ Wm1t, ushort* __restrict__ Wm2t,
    float* __restrict__ u1, float* __restrict__ v1,
    float* __restrict__ u2, float* __restrict__ v2,
    uint4* __restrict__ zero_base){
  const int b = blockIdx.x;
  const int tid = threadIdx.x;
  if (b < PREP_WB){
    int i = b*256 + tid;
    if (i < 8192){                              // W1t[n][k], N=128, K=64
      int n_ = i >> 6, k_ = i & 63;
      W1t[i] = f2bf(W1[(size_t)k_*128 + n_]);
    } else if (i < 16384){                      // W2t[n][k], N=64, K=128
      int j = i - 8192;
      int n_ = j >> 7, k_ = j & 127;
      W2t[j] = f2bf(W2[(size_t)k_*64 + n_]);
    } else if (i < 32768){                      // Wm1t[n][k], N=256, K=64
      int j = i - 16384;
      int n_ = j >> 6, k_ = j & 63;
      Wm1t[j] = f2bf(Wm1[(size_t)k_*256 + n_]);
    } else {                                    // Wm2t[n][k], N=256, K=256
      int j = i - 32768;
      int n_ = j >> 8, k_ = j & 255;
      Wm2t[j] = f2bf(Wm2[(size_t)k_*256 + n_]);
    }
    return;
  }
  if (b == PREP_WB){
    int t = tid;
    if (t < 64){                                // u1/v1 = W1 @ a1s / a1d
      float su = 0.f, sv = 0.f;
      for (int c = 0; c < 128; c++){ float w = W1[(size_t)t*128 + c]; su += w*a1s[c]; sv += w*a1d[c]; }
      u1[t] = su; v1[t] = sv;
    } else if (t < 192){                        // u2/v2 = W2 @ a2s / a2d
      int k = t - 64;
      float su = 0.f, sv = 0.f;
      for (int c = 0; c < 64; c++){ float w = W2[(size_t)k*64 + c]; su += w*a2s[c]; sv += w*a2d[c]; }
      u2[k] = su; v2[k] = sv;
    }
    return;
  }
  // zero blocks: 98 x 4KB = 401408 B covering cursor_b | as2 | ad2
  int z = b - (PREP_WB + 1);
  zero_base[(size_t)z*256 + tid] = (uint4){0u,0u,0u,0u};
}

// ---------------- prep 2: x f32->bf16, as1/ad1 = x.u1 / x.v1 ----------------

__global__ void prep_x_kernel(const float* __restrict__ x, const float* __restrict__ u1,
                              const float* __restrict__ v1, ushort* __restrict__ xb,
                              float* __restrict__ as1, float* __restrict__ ad1, int n){
  int gid = blockIdx.x*blockDim.x + threadIdx.x;
  int node = gid >> 6, lane = gid & 63;
  if (node >= n) return;
  float xv = x[(size_t)node*64 + lane];
  xb[(size_t)node*64 + lane] = f2bf(xv);
  float ps = xv * u1[lane], pd = xv * v1[lane];
  #pragma unroll
  for (int off = 32; off; off >>= 1){
    ps += __shfl_xor(ps, off);
    pd += __shfl_xor(pd, off);
  }
  if (lane == 0){ as1[node] = ps; ad1[node] = pd; }
}

// ---------------- fused GAT aggregation, C=64 ----------------
// wave per dst; chunk-of-64 softmax in lanes; (w,s) staged to LDS;
// gather: half-wave per edge (dword = 2ch/lane), unrolled 4 pairs.

template<bool BIASRELU>
__global__ __launch_bounds__(256) void aggc64_kernel(
    const int* __restrict__ rowptr, const int* __restrict__ csr_src,
    const ushort* __restrict__ h, const float* __restrict__ as,
    const float* __restrict__ ad, const float* __restrict__ bias,
    ushort* __restrict__ out, int n){
  __shared__ uint2 spair[4][72];
  int gid = blockIdx.x*blockDim.x + threadIdx.x;
  int dst = gid >> 6, lane = gid & 63;
  if (dst >= n) return;
  int wv = threadIdx.x >> 6;
  if (lane < 8) spair[wv][64 + lane] = (uint2){0u, 0u};   // zero tail once
  int r0 = rowptr[dst], r1 = rowptr[dst+1];
  float adv = ad[dst];
  const int hf = lane >> 5;
  const int ch = (lane & 31) * 2;
  float m = -INFINITY, denom = 0.f, acc0 = 0.f, acc1 = 0.f;
  for (int j0 = r0; j0 < r1; j0 += 64){
    int j = j0 + lane;
    int cnt = min(64, r1 - j0);
    bool valid = (j < r1);
    int s = valid ? csr_src[j] : 0;
    float e = -INFINITY;
    if (valid){
      e = as[s] + adv;
      e = (e > 0.f) ? e : 0.2f*e;
    }
    float cm = e;
    #pragma unroll
    for (int off = 32; off; off >>= 1) cm = fmaxf(cm, __shfl_xor(cm, off));
    float mn = fmaxf(m, cm);
    float w = valid ? __expf(e - mn) : 0.f;
    float csum = w;
    #pragma unroll
    for (int off = 32; off; off >>= 1) csum += __shfl_xor(csum, off);
    float scale = __expf(m - mn);          // first chunk: exp(-inf)=0
    denom = denom*scale + csum;
    acc0 *= scale; acc1 *= scale;
    m = mn;
    spair[wv][lane] = (uint2){__float_as_uint(w), (unsigned)s};
    for (int k = 0; k < cnt; k += 8){
      #pragma unroll
      for (int p = 0; p < 4; p++){
        uint2 pr = spair[wv][k + 2*p + hf];
        float wp = __uint_as_float(pr.x);
        unsigned hv = *(const unsigned*)(h + ((size_t)pr.y << 6) + ch);
        acc0 += wp * bflo(hv);
        acc1 += wp * bfhi(hv);
      }
    }
  }
  acc0 += __shfl_xor(acc0, 32);
  acc1 += __shfl_xor(acc1, 32);
  if (hf == 0){
    float inv = 1.f / denom;
    float o0 = acc0*inv, o1 = acc1*inv;
    if (BIASRELU){
      o0 = fmaxf(o0 + bias[ch],   0.f);
      o1 = fmaxf(o1 + bias[ch+1], 0.f);
    }
    unsigned pack = (unsigned)f2bf(o0) | ((unsigned)f2bf(o1) << 16);
    *(unsigned*)(out + ((size_t)dst << 6) + ch) = pack;
  }
}

// ---------------- bf16 MFMA GEMM, multi-N-stripe: C[M][0:NSTR*64] = A @ Bt^T ----------------
// grid (1, M/64). A streamed once; B (small, L2-resident) staged for all stripes per k-tile.

#define SWZ(row, byte_in_row) ((((row)*128) + (byte_in_row)) ^ (((row)&7) << 4))

template<int NSTR, bool BIAS, bool RELU, bool OUTBF16, bool ALPHA>
__global__ __launch_bounds__(256) void gemm_bf16_kernel(
    const ushort* __restrict__ A, const ushort* __restrict__ Bt,
    const float* __restrict__ bias, void* __restrict__ Cout,
    int M, int K, int N,
    const float* __restrict__ u2, const float* __restrict__ v2,
    float* __restrict__ as2, float* __restrict__ ad2){
  __shared__ unsigned char lds[8192 + NSTR*8192];   // As | Bs[stripes]
  const int tid = threadIdx.x;
  const int lane = tid & 63;
  const int wid = tid >> 6;
  const int wr = (wid >> 1) * 32;
  const int wc = (wid & 1) * 32;
  const int row0 = blockIdx.y * 64;

  f32x4 acc[NSTR][2][2];
  #pragma unroll
  for (int st = 0; st < NSTR; st++)
    #pragma unroll
    for (int i = 0; i < 2; i++)
      #pragma unroll
      for (int j = 0; j < 2; j++)
        acc[st][i][j] = (f32x4){0.f, 0.f, 0.f, 0.f};

  const int lrow = lane & 15;
  const int kgrp = (lane >> 4) * 16;

  for (int k0 = 0; k0 < K; k0 += 64){
    #pragma unroll
    for (int it = 0; it < 2; it++){
      int g = tid + it*256;
      int row = g >> 3, c8 = g & 7;
      int gr = row0 + row;
      uint4 v = {0u,0u,0u,0u};
      if (gr < M) v = *(const uint4*)(A + (size_t)gr*K + k0 + c8*8);
      *(uint4*)(lds + SWZ(row, c8*16)) = v;
    }
    #pragma unroll
    for (int it = 0; it < 2*NSTR; it++){
      int g = tid + it*256;
      int row = g >> 3, c8 = g & 7;                 // row = global n in [0, NSTR*64)
      uint4 v = *(const uint4*)(Bt + (size_t)row*K + k0 + c8*8);
      *(uint4*)(lds + 8192 + (row >> 6)*8192 + SWZ(row & 63, c8*16)) = v;
    }
    __syncthreads();
    #pragma unroll
    for (int kb = 0; kb < 2; kb++){
      int kbyte = kb*64 + kgrp;
      short8v a[2];
      #pragma unroll
      for (int mi = 0; mi < 2; mi++)
        a[mi] = *(const short8v*)(lds + SWZ(wr + mi*16 + lrow, kbyte));
      #pragma unroll
      for (int st = 0; st < NSTR; st++){
        short8v bfr[2];
        #pragma unroll
        for (int ni = 0; ni < 2; ni++)
          bfr[ni] = *(const short8v*)(lds + 8192 + st*8192 + SWZ(wc + ni*16 + lrow, kbyte));
        #pragma unroll
        for (int mi = 0; mi < 2; mi++)
          #pragma unroll
          for (int ni = 0; ni < 2; ni++)
            acc[st][mi][ni] = __builtin_amdgcn_mfma_f32_16x16x32_bf16(a[mi], bfr[ni], acc[st][mi][ni], 0, 0, 0);
      }
    }
    __syncthreads();
  }

  if constexpr (ALPHA){
    #pragma unroll
    for (int mi = 0; mi < 2; mi++){
      float pu[4] = {0.f,0.f,0.f,0.f}, pv[4] = {0.f,0.f,0.f,0.f};
      int rbase = row0 + wr + mi*16 + (lane >> 4)*4;
      #pragma unroll
      for (int st = 0; st < NSTR; st++){
        #pragma unroll
        for (int ni = 0; ni < 2; ni++){
          int c = st*64 + wc + ni*16 + (lane & 15);
          float bv = BIAS ? bias[c] : 0.f;
          float uc = u2[c], vc = v2[c];
          #pragma unroll
          for (int r = 0; r < 4; r++){
            float v = acc[st][mi][ni][r] + bv;
            if (RELU) v = fmaxf(v, 0.f);
            if (rbase + r < M)
              ((ushort*)Cout)[(size_t)(rbase+r)*N + c] = f2bf(v);
            pu[r] += v*uc; pv[r] += v*vc;
          }
        }
      }
      #pragma unroll
      for (int off = 8; off; off >>= 1){
        #pragma unroll
        for (int r = 0; r < 4; r++){
          pu[r] += __shfl_xor(pu[r], off);
          pv[r] += __shfl_xor(pv[r], off);
        }
      }
      if ((lane & 15) == 0){
        #pragma unroll
        for (int r = 0; r < 4; r++){
          if (rbase + r < M){
            atomicAdd(&as2[rbase+r], pu[r]);
            atomicAdd(&ad2[rbase+r], pv[r]);
          }
        }
      }
    }
  } else {
    #pragma unroll
    for (int st = 0; st < NSTR; st++){
      #pragma unroll
      for (int mi = 0; mi < 2; mi++){
        #pragma unroll
        for (int ni = 0; ni < 2; ni++){
          int c = st*64 + wc + ni*16 + (lane & 15);
          int rbase = row0 + wr + mi*16 + (lane >> 4)*4;
          float bv = BIAS ? bias[c] : 0.f;
          #pragma unroll
          for (int r = 0; r < 4; r++){
            int row = rbase + r;
            if (row >= M) continue;
            float v = acc[st][mi][ni][r] + bv;
            if (RELU) v = fmaxf(v, 0.f);
            if (OUTBF16) ((ushort*)Cout)[(size_t)row*N + c] = f2bf(v);
            else         ((float*)Cout)[(size_t)row*N + c] = v;
          }
        }
      }
    }
  }
}

// ---------------- launch ----------------

extern "C" void kernel_launch(void* const* d_in, const int* in_sizes, int n_in,
                              void* d_out, int out_size, void* d_ws, size_t ws_size,
                              hipStream_t stream){
  const float* x   = (const float*)d_in[0];
  const int*   ei  = (const int*)d_in[1];
  const float* W1  = (const float*)d_in[3];
  const float* a1s = (const float*)d_in[4];
  const float* a1d = (const float*)d_in[5];
  const float* b1  = (const float*)d_in[6];
  const float* W2  = (const float*)d_in[7];
  const float* a2s = (const float*)d_in[8];
  const float* a2d = (const float*)d_in[9];
  const float* b2  = (const float*)d_in[10];
  const float* Wm1 = (const float*)d_in[11];
  const float* bm1 = (const float*)d_in[12];
  const float* Wm2 = (const float*)d_in[13];
  const float* bm2 = (const float*)d_in[14];
  float* out = (float*)d_out;

  const int N = NNODES, E = NEDGES;
  const int TOT = E + N;

  char* w = (char*)d_ws;
  auto alloc = [&](size_t bytes)->void*{
    void* p = (void*)w;
    w += (bytes + 255) & ~(size_t)255;
    return p;
  };
  // zero region (written by prep_weights zero blocks): cursor_b | as2 | ad2 = 401408 B
  int*    cursor_b = (int*)alloc(NBUCK*4);            // 1024 B
  float*  as2      = (float*)alloc((size_t)N*4);      // 200192 B padded
  float*  ad2      = (float*)alloc((size_t)N*4);      // 200192 B padded
  uint2*  binned   = (uint2*)alloc((size_t)NBUCK*CAP*8);
  int*    rowptr   = (int*)alloc((size_t)(N+1)*4);
  int*    csr_src  = (int*)alloc((size_t)TOT*4);
  ushort* xb       = (ushort*)alloc((size_t)N*64*2);
  ushort* W1t      = (ushort*)alloc((size_t)64*128*2);
  ushort* W2t      = (ushort*)alloc((size_t)128*64*2);
  ushort* Wm1t     = (ushort*)alloc((size_t)64*256*2);
  ushort* Wm2t     = (ushort*)alloc((size_t)256*256*2);
  float*  u1       = (float*)alloc(128*4);
  float*  v1       = (float*)alloc(128*4);
  float*  u2       = (float*)alloc(128*4);
  float*  v2       = (float*)alloc(128*4);
  float*  as1      = (float*)alloc((size_t)N*4);
  float*  ad1      = (float*)alloc((size_t)N*4);
  ushort* aggx     = (ushort*)alloc((size_t)N*64*2);
  ushort* out1b    = (ushort*)alloc((size_t)N*128*2);
  ushort* h2b      = (ushort*)alloc((size_t)N*64*2);
  ushort* out2b    = (ushort*)alloc((size_t)N*64*2);
  ushort* hidb     = (ushort*)alloc((size_t)N*256*2);
  (void)ws_size; (void)n_in; (void)in_sizes; (void)out_size;

  // prep 1: weight transposes | u/v vectors | zero cursor_b/as2/ad2
  prep_weights_kernel<<<PREP_WB + 1 + PREP_ZB, 256, 0, stream>>>(
      W1, W2, Wm1, Wm2, a1s, a1d, a2s, a2d,
      W1t, W2t, Wm1t, Wm2t, u1, v1, u2, v2, (uint4*)cursor_b);
  // prep 2: x conversion + layer-1 alphas (needs u1/v1)
  prep_x_kernel<<<(N*64+255)/256, 256, 0, stream>>>(x, u1, v1, xb, as1, ad1, N);

  // CSR build (sorted by dst, coalesced writes)
  const int nbB = (TOT + PB_EDGES - 1) / PB_EDGES;    // 208
  bin_edges_kernel<<<nbB, 256, 0, stream>>>(ei, cursor_b, binned, E, N);
  build_csr_kernel<<<NBUCK_USED, 256, 0, stream>>>(binned, cursor_b, csr_src, rowptr, N, TOT);

  const int mb = (N + 63)/64;
  dim3 blk(256);
  const int nwave = (N*64 + 255)/256;

  // GAT layer 1: aggregate x (64ch), then W1 (+b1, relu, as2/ad2 alphas) via GEMM
  aggc64_kernel<false><<<nwave, 256, 0, stream>>>(rowptr, csr_src, xb, as1, ad1, nullptr, aggx, N);
  gemm_bf16_kernel<2,true,true,true,true><<<dim3(1, mb), blk, 0, stream>>>(
      aggx, W1t, b1, out1b, N, 64, 128, u2, v2, as2, ad2);
  // GAT layer 2: transform then aggregate
  gemm_bf16_kernel<1,false,false,true,false><<<dim3(1, mb), blk, 0, stream>>>(
      out1b, W2t, nullptr, h2b, N, 128, 64, nullptr, nullptr, nullptr, nullptr);
  aggc64_kernel<true><<<nwave, 256, 0, stream>>>(rowptr, csr_src, h2b, as2, ad2, b2, out2b, N);
  // MLP
  gemm_bf16_kernel<4,true,true ,true ,false><<<dim3(1, mb), blk, 0, stream>>>(
      out2b, Wm1t, bm1, hidb, N, 64, 256, nullptr, nullptr, nullptr, nullptr);
  gemm_bf16_kernel<4,true,false,false,false><<<dim3(1, mb), blk, 0, stream>>>(
      hidb, Wm2t, bm2, out, N, 256, 256, nullptr, nullptr, nullptr, nullptr);
}

// Round 10
// 245.821 us; speedup vs baseline: 1.6898x; 1.0386x over previous
//
#include <hip/hip_runtime.h>
#include <math.h>

#define NNODES 50000
#define NEDGES 800000
#define NBUCK  256          // buckets = dst >> 8 ; used: ceil(50000/256) = 196
#define NBUCK_USED ((NNODES + 255) >> 8)
#define CAP    6144         // max edges per bucket (mean 4352, sd ~66)
#define PB_EDGES 4096       // edges per bin_edges block

typedef __attribute__((ext_vector_type(8))) short short8v;
typedef __attribute__((ext_vector_type(4))) float f32x4;
typedef unsigned short ushort;

static __device__ __forceinline__ ushort f2bf(float f){
  union { float f; unsigned u; } v; v.f = f;
  unsigned r = (v.u + 0x7fffu + ((v.u >> 16) & 1u)) >> 16;   // RNE
  return (ushort)r;
}
static __device__ __forceinline__ float bflo(unsigned hv){
  union { unsigned u; float f; } v; v.u = hv << 16; return v.f;
}
static __device__ __forceinline__ float bfhi(unsigned hv){
  union { unsigned u; float f; } v; v.u = hv & 0xffff0000u; return v.f;
}

// ---------------- CSR build: two-level LDS-staged counting sort ----------------

__global__ __launch_bounds__(256) void bin_edges_kernel(
    const int* __restrict__ ei, int* __restrict__ cursor_b,
    uint2* __restrict__ binned, int E, int n){
  __shared__ int lcnt[NBUCK];
  __shared__ int lofs[NBUCK];
  __shared__ int gbase[NBUCK];
  __shared__ int sc[NBUCK];
  __shared__ uint2 stage[PB_EDGES];          // 32 KB
  const int tid = threadIdx.x;
  const int base = blockIdx.x * PB_EDGES;
  const int tot = E + n;
  const int cnt = min(PB_EDGES, tot - base);

  lcnt[tid] = 0;
  __syncthreads();

  uint2 ed[PB_EDGES/256];
  #pragma unroll
  for (int k = 0; k < PB_EDGES/256; k++){
    int idx = base + tid + k*256;            // coalesced
    if (idx < tot){
      int s, d;
      if (idx < E){ s = ei[idx]; d = ei[E+idx]; } else { s = idx - E; d = s; }
      ed[k].x = (unsigned)s; ed[k].y = (unsigned)d;
      atomicAdd(&lcnt[d >> 8], 1);
    }
  }
  __syncthreads();

  sc[tid] = lcnt[tid];
  __syncthreads();
  for (int off = 1; off < NBUCK; off <<= 1){
    int t = (tid >= off) ? sc[tid - off] : 0;
    __syncthreads();
    sc[tid] += t;
    __syncthreads();
  }
  lofs[tid] = sc[tid] - lcnt[tid];
  gbase[tid] = atomicAdd(&cursor_b[tid], lcnt[tid]);
  __syncthreads();
  lcnt[tid] = 0;                             // reuse as rank counters
  __syncthreads();

  #pragma unroll
  for (int k = 0; k < PB_EDGES/256; k++){
    int idx = base + tid + k*256;
    if (idx < tot){
      int b = ed[k].y >> 8;
      int r = atomicAdd(&lcnt[b], 1);
      stage[lofs[b] + r] = ed[k];
    }
  }
  __syncthreads();

  for (int idx = tid; idx < cnt; idx += 256){
    uint2 p = stage[idx];
    int b = p.y >> 8;
    binned[(size_t)b*CAP + gbase[b] + (idx - lofs[b])] = p;
  }
}

// per-bucket counting sort by dst -> csr_src (coalesced) + rowptr.
__global__ __launch_bounds__(256) void build_csr_kernel(
    const uint2* __restrict__ binned, const int* __restrict__ cursor_b,
    int* __restrict__ csr_src, int* __restrict__ rowptr, int n, int tot){
  __shared__ int bc[256];
  __shared__ int sc[256];
  __shared__ int cnt256[256];
  __shared__ int ofs[256];
  __shared__ int stage[CAP];                 // 24 KB
  const int b = blockIdx.x;
  const int tid = threadIdx.x;

  int c = cursor_b[tid];
  bc[tid] = c; sc[tid] = c;
  __syncthreads();
  for (int off = 1; off < 256; off <<= 1){
    int t = (tid >= off) ? sc[tid - off] : 0;
    __syncthreads();
    sc[tid] += t;
    __syncthreads();
  }
  const int base = sc[b] - bc[b];
  const int cnt = min(bc[b], CAP);

  cnt256[tid] = 0;
  __syncthreads();
  for (int i = tid; i < cnt; i += 256){
    int d = binned[(size_t)b*CAP + i].y & 255;
    atomicAdd(&cnt256[d], 1);
  }
  __syncthreads();
  sc[tid] = cnt256[tid];
  __syncthreads();
  for (int off = 1; off < 256; off <<= 1){
    int t = (tid >= off) ? sc[tid - off] : 0;
    __syncthreads();
    sc[tid] += t;
    __syncthreads();
  }
  ofs[tid] = sc[tid] - cnt256[tid];
  __syncthreads();
  cnt256[tid] = 0;
  __syncthreads();
  for (int i = tid; i < cnt; i += 256){
    uint2 p = binned[(size_t)b*CAP + i];
    int d = p.y & 255;
    int r = atomicAdd(&cnt256[d], 1);
    stage[ofs[d] + r] = (int)p.x;
  }
  __syncthreads();
  for (int i = tid; i < cnt; i += 256)
    csr_src[base + i] = stage[i];
  int node = b*256 + tid;
  if (node < n) rowptr[node] = base + ofs[tid];
  if (b == 0 && tid == 0) rowptr[n] = tot;
}

// ---------------- prep 1: weight transposes | folded vectors | zeroing ----------------
// grid: [0,384) weight transposes | 384 vecs | [385, 385+98) zero blocks

#define PREP_WB 384
#define PREP_ZB 98

__global__ __launch_bounds__(256) void prep_weights_kernel(
    const float* __restrict__ W1, const float* __restrict__ W2,
    const float* __restrict__ Wm1, const float* __restrict__ Wm2,
    const float* __restrict__ a1s, const float* __restrict__ a1d,
    const float* __restrict__ a2s, const float* __restrict__ a2d,
    ushort* __restrict__ W1t, ushort* __restrict__ W2t,
    ushort* __restrict__ Wm1t, ushort* __restrict__ Wm2t,
    float* __restrict__ u1, float* __restrict__ v1,
    float* __restrict__ u2, float* __restrict__ v2,
    uint4* __restrict__ zero_base){
  const int b = blockIdx.x;
  const int tid = threadIdx.x;
  if (b < PREP_WB){
    int i = b*256 + tid;
    if (i < 8192){                              // W1t[n][k], N=128, K=64
      int n_ = i >> 6, k_ = i & 63;
      W1t[i] = f2bf(W1[(size_t)k_*128 + n_]);
    } else if (i < 16384){                      // W2t[n][k], N=64, K=128
      int j = i - 8192;
      int n_ = j >> 7, k_ = j & 127;
      W2t[j] = f2bf(W2[(size_t)k_*64 + n_]);
    } else if (i < 32768){                      // Wm1t[n][k], N=256, K=64
      int j = i - 16384;
      int n_ = j >> 6, k_ = j & 63;
      Wm1t[j] = f2bf(Wm1[(size_t)k_*256 + n_]);
    } else {                                    // Wm2t[n][k], N=256, K=256
      int j = i - 32768;
      int n_ = j >> 8, k_ = j & 255;
      Wm2t[j] = f2bf(Wm2[(size_t)k_*256 + n_]);
    }
    return;
  }
  if (b == PREP_WB){
    int t = tid;
    if (t < 64){                                // u1/v1 = W1 @ a1s / a1d
      float su = 0.f, sv = 0.f;
      for (int c = 0; c < 128; c++){ float w = W1[(size_t)t*128 + c]; su += w*a1s[c]; sv += w*a1d[c]; }
      u1[t] = su; v1[t] = sv;
    } else if (t < 192){                        // u2/v2 = W2 @ a2s / a2d
      int k = t - 64;
      float su = 0.f, sv = 0.f;
      for (int c = 0; c < 64; c++){ float w = W2[(size_t)k*64 + c]; su += w*a2s[c]; sv += w*a2d[c]; }
      u2[k] = su; v2[k] = sv;
    }
    return;
  }
  // zero blocks: 98 x 4KB = 401408 B covering cursor_b | as2 | ad2
  int z = b - (PREP_WB + 1);
  zero_base[(size_t)z*256 + tid] = (uint4){0u,0u,0u,0u};
}

// ---------------- prep 2: x f32->bf16, as1/ad1 = x.u1 / x.v1 ----------------

__global__ void prep_x_kernel(const float* __restrict__ x, const float* __restrict__ u1,
                              const float* __restrict__ v1, ushort* __restrict__ xb,
                              float* __restrict__ as1, float* __restrict__ ad1, int n){
  int gid = blockIdx.x*blockDim.x + threadIdx.x;
  int node = gid >> 6, lane = gid & 63;
  if (node >= n) return;
  float xv = x[(size_t)node*64 + lane];
  xb[(size_t)node*64 + lane] = f2bf(xv);
  float ps = xv * u1[lane], pd = xv * v1[lane];
  #pragma unroll
  for (int off = 32; off; off >>= 1){
    ps += __shfl_xor(ps, off);
    pd += __shfl_xor(pd, off);
  }
  if (lane == 0){ as1[node] = ps; ad1[node] = pd; }
}

// ---------------- fused GAT aggregation, C=64 ----------------
// wave per dst; chunk-of-64 softmax in lanes; (w,s) staged to LDS;
// gather: half-wave per edge (dword = 2ch/lane), unrolled 4 pairs.

template<bool BIASRELU>
__global__ __launch_bounds__(256) void aggc64_kernel(
    const int* __restrict__ rowptr, const int* __restrict__ csr_src,
    const ushort* __restrict__ h, const float* __restrict__ as,
    const float* __restrict__ ad, const float* __restrict__ bias,
    ushort* __restrict__ out, int n){
  __shared__ uint2 spair[4][72];
  int gid = blockIdx.x*blockDim.x + threadIdx.x;
  int dst = gid >> 6, lane = gid & 63;
  if (dst >= n) return;
  int wv = threadIdx.x >> 6;
  if (lane < 8) spair[wv][64 + lane] = (uint2){0u, 0u};   // zero tail once
  int r0 = rowptr[dst], r1 = rowptr[dst+1];
  float adv = ad[dst];
  const int hf = lane >> 5;
  const int ch = (lane & 31) * 2;
  float m = -INFINITY, denom = 0.f, acc0 = 0.f, acc1 = 0.f;
  for (int j0 = r0; j0 < r1; j0 += 64){
    int j = j0 + lane;
    int cnt = min(64, r1 - j0);
    bool valid = (j < r1);
    int s = valid ? csr_src[j] : 0;
    float e = -INFINITY;
    if (valid){
      e = as[s] + adv;
      e = (e > 0.f) ? e : 0.2f*e;
    }
    float cm = e;
    #pragma unroll
    for (int off = 32; off; off >>= 1) cm = fmaxf(cm, __shfl_xor(cm, off));
    float mn = fmaxf(m, cm);
    float w = valid ? __expf(e - mn) : 0.f;
    float csum = w;
    #pragma unroll
    for (int off = 32; off; off >>= 1) csum += __shfl_xor(csum, off);
    float scale = __expf(m - mn);          // first chunk: exp(-inf)=0
    denom = denom*scale + csum;
    acc0 *= scale; acc1 *= scale;
    m = mn;
    spair[wv][lane] = (uint2){__float_as_uint(w), (unsigned)s};
    for (int k = 0; k < cnt; k += 8){
      #pragma unroll
      for (int p = 0; p < 4; p++){
        uint2 pr = spair[wv][k + 2*p + hf];
        float wp = __uint_as_float(pr.x);
        unsigned hv = *(const unsigned*)(h + ((size_t)pr.y << 6) + ch);
        acc0 += wp * bflo(hv);
        acc1 += wp * bfhi(hv);
      }
    }
  }
  acc0 += __shfl_xor(acc0, 32);
  acc1 += __shfl_xor(acc1, 32);
  if (hf == 0){
    float inv = 1.f / denom;
    float o0 = acc0*inv, o1 = acc1*inv;
    if (BIASRELU){
      o0 = fmaxf(o0 + bias[ch],   0.f);
      o1 = fmaxf(o1 + bias[ch+1], 0.f);
    }
    unsigned pack = (unsigned)f2bf(o0) | ((unsigned)f2bf(o1) << 16);
    *(unsigned*)(out + ((size_t)dst << 6) + ch) = pack;
  }
}

// ---------------- bf16 MFMA GEMM: C[M][N] = A[M][K] @ Bt[N][K]^T ----------------
// 64x64 tile, BK=64, 2D grid (high occupancy). ALPHA: as2/ad2 row-dot partials via atomicAdd.

#define SWZ(row, byte_in_row) ((((row)*128) + (byte_in_row)) ^ (((row)&7) << 4))

template<bool BIAS, bool RELU, bool OUTBF16, bool ALPHA>
__global__ __launch_bounds__(256) void gemm_bf16_kernel(
    const ushort* __restrict__ A, const ushort* __restrict__ Bt,
    const float* __restrict__ bias, void* __restrict__ Cout,
    int M, int K, int N,
    const float* __restrict__ u2, const float* __restrict__ v2,
    float* __restrict__ as2, float* __restrict__ ad2){
  __shared__ unsigned char lds[16384];      // As: [0,8K)  Bs: [8K,16K)
  const int tid = threadIdx.x;
  const int lane = tid & 63;
  const int wid = tid >> 6;
  const int wr = (wid >> 1) * 32;
  const int wc = (wid & 1) * 32;
  const int row0 = blockIdx.y * 64;
  const int col0 = blockIdx.x * 64;

  f32x4 acc[2][2];
  #pragma unroll
  for (int i = 0; i < 2; i++)
    #pragma unroll
    for (int j = 0; j < 2; j++)
      acc[i][j] = (f32x4){0.f, 0.f, 0.f, 0.f};

  const int lrow = lane & 15;
  const int kgrp = (lane >> 4) * 16;

  for (int k0 = 0; k0 < K; k0 += 64){
    #pragma unroll
    for (int it = 0; it < 2; it++){
      int g = tid + it*256;
      int row = g >> 3, c8 = g & 7;
      int gr = row0 + row;
      uint4 v = {0u,0u,0u,0u};
      if (gr < M) v = *(const uint4*)(A + (size_t)gr*K + k0 + c8*8);
      *(uint4*)(lds + SWZ(row, c8*16)) = v;
    }
    #pragma unroll
    for (int it = 0; it < 2; it++){
      int g = tid + it*256;
      int row = g >> 3, c8 = g & 7;
      uint4 v = *(const uint4*)(Bt + (size_t)(col0 + row)*K + k0 + c8*8);
      *(uint4*)(lds + 8192 + SWZ(row, c8*16)) = v;
    }
    __syncthreads();
    #pragma unroll
    for (int kb = 0; kb < 2; kb++){
      int kbyte = kb*64 + kgrp;
      short8v a[2], b[2];
      #pragma unroll
      for (int mi = 0; mi < 2; mi++)
        a[mi] = *(const short8v*)(lds + SWZ(wr + mi*16 + lrow, kbyte));
      #pragma unroll
      for (int ni = 0; ni < 2; ni++)
        b[ni] = *(const short8v*)(lds + 8192 + SWZ(wc + ni*16 + lrow, kbyte));
      #pragma unroll
      for (int mi = 0; mi < 2; mi++)
        #pragma unroll
        for (int ni = 0; ni < 2; ni++)
          acc[mi][ni] = __builtin_amdgcn_mfma_f32_16x16x32_bf16(a[mi], b[ni], acc[mi][ni], 0, 0, 0);
    }
    __syncthreads();
  }

  if constexpr (ALPHA){
    #pragma unroll
    for (int mi = 0; mi < 2; mi++){
      float pu[4] = {0.f,0.f,0.f,0.f}, pv[4] = {0.f,0.f,0.f,0.f};
      int rbase = row0 + wr + mi*16 + (lane >> 4)*4;
      #pragma unroll
      for (int ni = 0; ni < 2; ni++){
        int c = col0 + wc + ni*16 + (lane & 15);
        float bv = BIAS ? bias[c] : 0.f;
        float uc = u2[c], vc = v2[c];
        #pragma unroll
        for (int r = 0; r < 4; r++){
          float v = acc[mi][ni][r] + bv;
          if (RELU) v = fmaxf(v, 0.f);
          if (rbase + r < M)
            ((ushort*)Cout)[(size_t)(rbase+r)*N + c] = f2bf(v);
          pu[r] += v*uc; pv[r] += v*vc;
        }
      }
      #pragma unroll
      for (int off = 8; off; off >>= 1){
        #pragma unroll
        for (int r = 0; r < 4; r++){
          pu[r] += __shfl_xor(pu[r], off);
          pv[r] += __shfl_xor(pv[r], off);
        }
      }
      if ((lane & 15) == 0){
        #pragma unroll
        for (int r = 0; r < 4; r++){
          if (rbase + r < M){
            atomicAdd(&as2[rbase+r], pu[r]);
            atomicAdd(&ad2[rbase+r], pv[r]);
          }
        }
      }
    }
  } else {
    #pragma unroll
    for (int mi = 0; mi < 2; mi++){
      #pragma unroll
      for (int ni = 0; ni < 2; ni++){
        int c = col0 + wc + ni*16 + (lane & 15);
        int rbase = row0 + wr + mi*16 + (lane >> 4)*4;
        float bv = BIAS ? bias[c] : 0.f;
        #pragma unroll
        for (int r = 0; r < 4; r++){
          int row = rbase + r;
          if (row >= M) continue;
          float v = acc[mi][ni][r] + bv;
          if (RELU) v = fmaxf(v, 0.f);
          if (OUTBF16) ((ushort*)Cout)[(size_t)row*N + c] = f2bf(v);
          else         ((float*)Cout)[(size_t)row*N + c] = v;
        }
      }
    }
  }
}

// ---------------- launch ----------------

extern "C" void kernel_launch(void* const* d_in, const int* in_sizes, int n_in,
                              void* d_out, int out_size, void* d_ws, size_t ws_size,
                              hipStream_t stream){
  const float* x   = (const float*)d_in[0];
  const int*   ei  = (const int*)d_in[1];
  const float* W1  = (const float*)d_in[3];
  const float* a1s = (const float*)d_in[4];
  const float* a1d = (const float*)d_in[5];
  const float* b1  = (const float*)d_in[6];
  const float* W2  = (const float*)d_in[7];
  const float* a2s = (const float*)d_in[8];
  const float* a2d = (const float*)d_in[9];
  const float* b2  = (const float*)d_in[10];
  const float* Wm1 = (const float*)d_in[11];
  const float* bm1 = (const float*)d_in[12];
  const float* Wm2 = (const float*)d_in[13];
  const float* bm2 = (const float*)d_in[14];
  float* out = (float*)d_out;

  const int N = NNODES, E = NEDGES;
  const int TOT = E + N;

  char* w = (char*)d_ws;
  auto alloc = [&](size_t bytes)->void*{
    void* p = (void*)w;
    w += (bytes + 255) & ~(size_t)255;
    return p;
  };
  // zero region (written by prep_weights zero blocks): cursor_b | as2 | ad2 = 401408 B
  int*    cursor_b = (int*)alloc(NBUCK*4);            // 1024 B
  float*  as2      = (float*)alloc((size_t)N*4);      // 200192 B padded
  float*  ad2      = (float*)alloc((size_t)N*4);      // 200192 B padded
  uint2*  binned   = (uint2*)alloc((size_t)NBUCK*CAP*8);
  int*    rowptr   = (int*)alloc((size_t)(N+1)*4);
  int*    csr_src  = (int*)alloc((size_t)TOT*4);
  ushort* xb       = (ushort*)alloc((size_t)N*64*2);
  ushort* W1t      = (ushort*)alloc((size_t)64*128*2);
  ushort* W2t      = (ushort*)alloc((size_t)128*64*2);
  ushort* Wm1t     = (ushort*)alloc((size_t)64*256*2);
  ushort* Wm2t     = (ushort*)alloc((size_t)256*256*2);
  float*  u1       = (float*)alloc(128*4);
  float*  v1       = (float*)alloc(128*4);
  float*  u2       = (float*)alloc(128*4);
  float*  v2       = (float*)alloc(128*4);
  float*  as1      = (float*)alloc((size_t)N*4);
  float*  ad1      = (float*)alloc((size_t)N*4);
  ushort* aggx     = (ushort*)alloc((size_t)N*64*2);
  ushort* out1b    = (ushort*)alloc((size_t)N*128*2);
  ushort* h2b      = (ushort*)alloc((size_t)N*64*2);
  ushort* out2b    = (ushort*)alloc((size_t)N*64*2);
  ushort* hidb     = (ushort*)alloc((size_t)N*256*2);
  (void)ws_size; (void)n_in; (void)in_sizes; (void)out_size;

  // prep 1: weight transposes | u/v vectors | zero cursor_b/as2/ad2
  prep_weights_kernel<<<PREP_WB + 1 + PREP_ZB, 256, 0, stream>>>(
      W1, W2, Wm1, Wm2, a1s, a1d, a2s, a2d,
      W1t, W2t, Wm1t, Wm2t, u1, v1, u2, v2, (uint4*)cursor_b);
  // prep 2: x conversion + layer-1 alphas (needs u1/v1)
  prep_x_kernel<<<(N*64+255)/256, 256, 0, stream>>>(x, u1, v1, xb, as1, ad1, N);

  // CSR build (sorted by dst, coalesced writes)
  const int nbB = (TOT + PB_EDGES - 1) / PB_EDGES;    // 208
  bin_edges_kernel<<<nbB, 256, 0, stream>>>(ei, cursor_b, binned, E, N);
  build_csr_kernel<<<NBUCK_USED, 256, 0, stream>>>(binned, cursor_b, csr_src, rowptr, N, TOT);

  const int mb = (N + 63)/64;
  dim3 blk(256);
  const int nwave = (N*64 + 255)/256;

  // GAT layer 1: aggregate x (64ch), then W1 (+b1, relu, as2/ad2 alphas) via GEMM
  aggc64_kernel<false><<<nwave, 256, 0, stream>>>(rowptr, csr_src, xb, as1, ad1, nullptr, aggx, N);
  gemm_bf16_kernel<true,true,true,true><<<dim3(2, mb), blk, 0, stream>>>(
      aggx, W1t, b1, out1b, N, 64, 128, u2, v2, as2, ad2);
  // GAT layer 2: transform then aggregate
  gemm_bf16_kernel<false,false,true,false><<<dim3(1, mb), blk, 0, stream>>>(
      out1b, W2t, nullptr, h2b, N, 128, 64, nullptr, nullptr, nullptr, nullptr);
  aggc64_kernel<true><<<nwave, 256, 0, stream>>>(rowptr, csr_src, h2b, as2, ad2, b2, out2b, N);
  // MLP
  gemm_bf16_kernel<true,true ,true ,false><<<dim3(4, mb), blk, 0, stream>>>(
      out2b, Wm1t, bm1, hidb, N, 64, 256, nullptr, nullptr, nullptr, nullptr);
  gemm_bf16_kernel<true,false,false,false><<<dim3(4, mb), blk, 0, stream>>>(
      hidb, Wm2t, bm2, out, N, 256, 256, nullptr, nullptr, nullptr, nullptr);
}

// Round 12
// 234.205 us; speedup vs baseline: 1.7736x; 1.0496x over previous
//
#include <hip/hip_runtime.h>
#include <math.h>

#define NNODES 50000
#define NEDGES 800000
#define NBUCK  256          // buckets = dst >> 8 ; used: ceil(50000/256) = 196
#define NBUCK_USED ((NNODES + 255) >> 8)
#define CAP    6144         // max edges per bucket (mean 4352, sd ~66)
#define PB_EDGES 4096       // edges per bin_edges block
#define BIN_B   ((NEDGES + NNODES + PB_EDGES - 1) / PB_EDGES)   // 208
#define XPREP_B ((NNODES*64 + 255) / 256)                        // 12500

typedef __attribute__((ext_vector_type(8))) short short8v;
typedef __attribute__((ext_vector_type(4))) float f32x4;
typedef unsigned short ushort;

static __device__ __forceinline__ ushort f2bf(float f){
  union { float f; unsigned u; } v; v.f = f;
  unsigned r = (v.u + 0x7fffu + ((v.u >> 16) & 1u)) >> 16;   // RNE
  return (ushort)r;
}
static __device__ __forceinline__ float bflo(unsigned hv){
  union { unsigned u; float f; } v; v.u = hv << 16; return v.f;
}
static __device__ __forceinline__ float bfhi(unsigned hv){
  union { unsigned u; float f; } v; v.u = hv & 0xffff0000u; return v.f;
}

// ---------------- CSR build pass 1 + x-prep (merged, independent block ranges) ----------------
// blocks [0,BIN_B): bin packed edges (bucket<<24 | src<<8 | dst&255) into per-bucket runs.
// blocks [BIN_B, BIN_B+XPREP_B): x f32->bf16 + as1/ad1 = x.u1 / x.v1 (u1/v1 from prep_weights).

__global__ __launch_bounds__(256) void bin_edges_kernel(
    const int* __restrict__ ei, int* __restrict__ cursor_b,
    unsigned* __restrict__ binned,
    const float* __restrict__ x, const float* __restrict__ u1, const float* __restrict__ v1,
    ushort* __restrict__ xb, float* __restrict__ as1, float* __restrict__ ad1,
    int E, int n){
  __shared__ int lcnt[NBUCK];
  __shared__ int lofs[NBUCK];
  __shared__ int gbase[NBUCK];
  __shared__ int sc[NBUCK];
  __shared__ unsigned stage[PB_EDGES];       // 16 KB
  const int tid = threadIdx.x;
  const int blk = blockIdx.x;

  if (blk >= BIN_B){
    // ---- x-prep part ----
    int gid = (blk - BIN_B)*256 + tid;
    int node = gid >> 6, lane = gid & 63;
    if (node >= n) return;
    float xv = x[(size_t)node*64 + lane];
    xb[(size_t)node*64 + lane] = f2bf(xv);
    float ps = xv * u1[lane], pd = xv * v1[lane];
    #pragma unroll
    for (int off = 32; off; off >>= 1){
      ps += __shfl_xor(ps, off);
      pd += __shfl_xor(pd, off);
    }
    if (lane == 0){ as1[node] = ps; ad1[node] = pd; }
    return;
  }

  const int base = blk * PB_EDGES;
  const int tot = E + n;
  const int cnt = min(PB_EDGES, tot - base);

  lcnt[tid] = 0;
  __syncthreads();

  unsigned ed[PB_EDGES/256];
  #pragma unroll
  for (int k = 0; k < PB_EDGES/256; k++){
    int idx = base + tid + k*256;            // coalesced
    if (idx < tot){
      int s, d;
      if (idx < E){ s = ei[idx]; d = ei[E+idx]; } else { s = idx - E; d = s; }
      unsigned bkt = (unsigned)d >> 8;
      ed[k] = (bkt << 24) | ((unsigned)s << 8) | ((unsigned)d & 255u);
      atomicAdd(&lcnt[bkt], 1);
    }
  }
  __syncthreads();

  sc[tid] = lcnt[tid];
  __syncthreads();
  for (int off = 1; off < NBUCK; off <<= 1){
    int t = (tid >= off) ? sc[tid - off] : 0;
    __syncthreads();
    sc[tid] += t;
    __syncthreads();
  }
  lofs[tid] = sc[tid] - lcnt[tid];
  gbase[tid] = atomicAdd(&cursor_b[tid], lcnt[tid]);
  __syncthreads();
  lcnt[tid] = 0;                             // reuse as rank counters
  __syncthreads();

  #pragma unroll
  for (int k = 0; k < PB_EDGES/256; k++){
    int idx = base + tid + k*256;
    if (idx < tot){
      int b = ed[k] >> 24;
      int r = atomicAdd(&lcnt[b], 1);
      stage[lofs[b] + r] = ed[k];
    }
  }
  __syncthreads();

  for (int idx = tid; idx < cnt; idx += 256){
    unsigned p = stage[idx];
    int b = p >> 24;
    binned[(size_t)b*CAP + gbase[b] + (idx - lofs[b])] = p;
  }
}

// per-bucket counting sort by dst -> csr_src (coalesced) + rowptr.
__global__ __launch_bounds__(256) void build_csr_kernel(
    const unsigned* __restrict__ binned, const int* __restrict__ cursor_b,
    int* __restrict__ csr_src, int* __restrict__ rowptr, int n, int tot){
  __shared__ int bc[256];
  __shared__ int sc[256];
  __shared__ int cnt256[256];
  __shared__ int ofs[256];
  __shared__ int stage[CAP];                 // 24 KB
  const int b = blockIdx.x;
  const int tid = threadIdx.x;

  int c = cursor_b[tid];
  bc[tid] = c; sc[tid] = c;
  __syncthreads();
  for (int off = 1; off < 256; off <<= 1){
    int t = (tid >= off) ? sc[tid - off] : 0;
    __syncthreads();
    sc[tid] += t;
    __syncthreads();
  }
  const int base = sc[b] - bc[b];
  const int cnt = min(bc[b], CAP);

  cnt256[tid] = 0;
  __syncthreads();
  for (int i = tid; i < cnt; i += 256){
    int d = binned[(size_t)b*CAP + i] & 255;
    atomicAdd(&cnt256[d], 1);
  }
  __syncthreads();
  sc[tid] = cnt256[tid];
  __syncthreads();
  for (int off = 1; off < 256; off <<= 1){
    int t = (tid >= off) ? sc[tid - off] : 0;
    __syncthreads();
    sc[tid] += t;
    __syncthreads();
  }
  ofs[tid] = sc[tid] - cnt256[tid];
  __syncthreads();
  cnt256[tid] = 0;
  __syncthreads();
  for (int i = tid; i < cnt; i += 256){
    unsigned p = binned[(size_t)b*CAP + i];
    int d = p & 255;
    int r = atomicAdd(&cnt256[d], 1);
    stage[ofs[d] + r] = (int)((p >> 8) & 0xffffu);
  }
  __syncthreads();
  for (int i = tid; i < cnt; i += 256)
    csr_src[base + i] = stage[i];
  int node = b*256 + tid;
  if (node < n) rowptr[node] = base + ofs[tid];
  if (b == 0 && tid == 0) rowptr[n] = tot;
}

// ---------------- prep 1: weight transposes | folded vectors | zeroing ----------------
// grid: [0,384) weight transposes | 384 vecs | [385, 385+98) zero blocks

#define PREP_WB 384
#define PREP_ZB 98

__global__ __launch_bounds__(256) void prep_weights_kernel(
    const float* __restrict__ W1, const float* __restrict__ W2,
    const float* __restrict__ Wm1, const float* __restrict__ Wm2,
    const float* __restrict__ a1s, const float* __restrict__ a1d,
    const float* __restrict__ a2s, const float* __restrict__ a2d,
    ushort* __restrict__ W1t, ushort* __restrict__ W2t,
    ushort* __restrict__ Wm1t, ushort* __restrict__ Wm2t,
    float* __restrict__ u1, float* __restrict__ v1,
    float* __restrict__ u2, float* __restrict__ v2,
    uint4* __restrict__ zero_base){
  const int b = blockIdx.x;
  const int tid = threadIdx.x;
  if (b < PREP_WB){
    int i = b*256 + tid;
    if (i < 8192){                              // W1t[n][k], N=128, K=64
      int n_ = i >> 6, k_ = i & 63;
      W1t[i] = f2bf(W1[(size_t)k_*128 + n_]);
    } else if (i < 16384){                      // W2t[n][k], N=64, K=128
      int j = i - 8192;
      int n_ = j >> 7, k_ = j & 127;
      W2t[j] = f2bf(W2[(size_t)k_*64 + n_]);
    } else if (i < 32768){                      // Wm1t[n][k], N=256, K=64
      int j = i - 16384;
      int n_ = j >> 6, k_ = j & 63;
      Wm1t[j] = f2bf(Wm1[(size_t)k_*256 + n_]);
    } else {                                    // Wm2t[n][k], N=256, K=256
      int j = i - 32768;
      int n_ = j >> 8, k_ = j & 255;
      Wm2t[j] = f2bf(Wm2[(size_t)k_*256 + n_]);
    }
    return;
  }
  if (b == PREP_WB){
    int t = tid;
    if (t < 64){                                // u1/v1 = W1 @ a1s / a1d
      float su = 0.f, sv = 0.f;
      for (int c = 0; c < 128; c++){ float w = W1[(size_t)t*128 + c]; su += w*a1s[c]; sv += w*a1d[c]; }
      u1[t] = su; v1[t] = sv;
    } else if (t < 192){                        // u2/v2 = W2 @ a2s / a2d
      int k = t - 64;
      float su = 0.f, sv = 0.f;
      for (int c = 0; c < 64; c++){ float w = W2[(size_t)k*64 + c]; su += w*a2s[c]; sv += w*a2d[c]; }
      u2[k] = su; v2[k] = sv;
    }
    return;
  }
  // zero blocks: 98 x 4KB = 401408 B covering cursor_b | as2 | ad2
  int z = b - (PREP_WB + 1);
  zero_base[(size_t)z*256 + tid] = (uint4){0u,0u,0u,0u};
}

// ---------------- fused GAT aggregation, C=64 ----------------
// wave per dst (scalarized via readfirstlane); chunk-of-64 softmax in lanes;
// (w,s) staged to LDS; gather: half-wave per edge (dword = 2ch/lane), 4 pairs unrolled.

template<bool BIASRELU>
__global__ __launch_bounds__(256) void aggc64_kernel(
    const int* __restrict__ rowptr, const int* __restrict__ csr_src,
    const ushort* __restrict__ h, const float* __restrict__ as,
    const float* __restrict__ ad, const float* __restrict__ bias,
    ushort* __restrict__ out, int n){
  __shared__ uint2 spair[4][72];
  int gid = blockIdx.x*blockDim.x + threadIdx.x;
  int dst = __builtin_amdgcn_readfirstlane(gid >> 6);   // wave-uniform -> SGPR, scalar loads
  int lane = threadIdx.x & 63;
  if (dst >= n) return;
  int wv = threadIdx.x >> 6;
  if (lane < 8) spair[wv][64 + lane] = (uint2){0u, 0u};   // zero tail once
  int r0 = rowptr[dst], r1 = rowptr[dst+1];
  float adv = ad[dst];
  const int hf = lane >> 5;
  const int ch = (lane & 31) * 2;
  float m = -INFINITY, denom = 0.f, acc0 = 0.f, acc1 = 0.f;
  for (int j0 = r0; j0 < r1; j0 += 64){
    int j = j0 + lane;
    int cnt = min(64, r1 - j0);
    bool valid = (j < r1);
    int s = valid ? csr_src[j] : 0;
    float e = -INFINITY;
    if (valid){
      e = as[s] + adv;
      e = (e > 0.f) ? e : 0.2f*e;
    }
    float cm = e;
    #pragma unroll
    for (int off = 32; off; off >>= 1) cm = fmaxf(cm, __shfl_xor(cm, off));
    float mn = fmaxf(m, cm);
    float w = valid ? __expf(e - mn) : 0.f;
    float csum = w;
    #pragma unroll
    for (int off = 32; off; off >>= 1) csum += __shfl_xor(csum, off);
    float scale = __expf(m - mn);          // first chunk: exp(-inf)=0
    denom = denom*scale + csum;
    acc0 *= scale; acc1 *= scale;
    m = mn;
    spair[wv][lane] = (uint2){__float_as_uint(w), (unsigned)s};
    for (int k = 0; k < cnt; k += 8){
      #pragma unroll
      for (int p = 0; p < 4; p++){
        uint2 pr = spair[wv][k + 2*p + hf];
        float wp = __uint_as_float(pr.x);
        unsigned hv = *(const unsigned*)(h + ((size_t)pr.y << 6) + ch);
        acc0 += wp * bflo(hv);
        acc1 += wp * bfhi(hv);
      }
    }
  }
  acc0 += __shfl_xor(acc0, 32);
  acc1 += __shfl_xor(acc1, 32);
  if (hf == 0){
    float inv = 1.f / denom;
    float o0 = acc0*inv, o1 = acc1*inv;
    if (BIASRELU){
      o0 = fmaxf(o0 + bias[ch],   0.f);
      o1 = fmaxf(o1 + bias[ch+1], 0.f);
    }
    unsigned pack = (unsigned)f2bf(o0) | ((unsigned)f2bf(o1) << 16);
    *(unsigned*)(out + ((size_t)dst << 6) + ch) = pack;
  }
}

// ---------------- bf16 MFMA GEMM: C[M][N] = A[M][K] @ Bt[N][K]^T ----------------
// 64x64 tile, BK=64, 2D grid (high occupancy). ALPHA: as2/ad2 row-dot partials via atomicAdd.

#define SWZ(row, byte_in_row) ((((row)*128) + (byte_in_row)) ^ (((row)&7) << 4))

template<bool BIAS, bool RELU, bool OUTBF16, bool ALPHA>
__global__ __launch_bounds__(256) void gemm_bf16_kernel(
    const ushort* __restrict__ A, const ushort* __restrict__ Bt,
    const float* __restrict__ bias, void* __restrict__ Cout,
    int M, int K, int N,
    const float* __restrict__ u2, const float* __restrict__ v2,
    float* __restrict__ as2, float* __restrict__ ad2){
  __shared__ unsigned char lds[16384];      // As: [0,8K)  Bs: [8K,16K)
  const int tid = threadIdx.x;
  const int lane = tid & 63;
  const int wid = tid >> 6;
  const int wr = (wid >> 1) * 32;
  const int wc = (wid & 1) * 32;
  const int row0 = blockIdx.y * 64;
  const int col0 = blockIdx.x * 64;

  f32x4 acc[2][2];
  #pragma unroll
  for (int i = 0; i < 2; i++)
    #pragma unroll
    for (int j = 0; j < 2; j++)
      acc[i][j] = (f32x4){0.f, 0.f, 0.f, 0.f};

  const int lrow = lane & 15;
  const int kgrp = (lane >> 4) * 16;

  for (int k0 = 0; k0 < K; k0 += 64){
    #pragma unroll
    for (int it = 0; it < 2; it++){
      int g = tid + it*256;
      int row = g >> 3, c8 = g & 7;
      int gr = row0 + row;
      uint4 v = {0u,0u,0u,0u};
      if (gr < M) v = *(const uint4*)(A + (size_t)gr*K + k0 + c8*8);
      *(uint4*)(lds + SWZ(row, c8*16)) = v;
    }
    #pragma unroll
    for (int it = 0; it < 2; it++){
      int g = tid + it*256;
      int row = g >> 3, c8 = g & 7;
      uint4 v = *(const uint4*)(Bt + (size_t)(col0 + row)*K + k0 + c8*8);
      *(uint4*)(lds + 8192 + SWZ(row, c8*16)) = v;
    }
    __syncthreads();
    #pragma unroll
    for (int kb = 0; kb < 2; kb++){
      int kbyte = kb*64 + kgrp;
      short8v a[2], b[2];
      #pragma unroll
      for (int mi = 0; mi < 2; mi++)
        a[mi] = *(const short8v*)(lds + SWZ(wr + mi*16 + lrow, kbyte));
      #pragma unroll
      for (int ni = 0; ni < 2; ni++)
        b[ni] = *(const short8v*)(lds + 8192 + SWZ(wc + ni*16 + lrow, kbyte));
      #pragma unroll
      for (int mi = 0; mi < 2; mi++)
        #pragma unroll
        for (int ni = 0; ni < 2; ni++)
          acc[mi][ni] = __builtin_amdgcn_mfma_f32_16x16x32_bf16(a[mi], b[ni], acc[mi][ni], 0, 0, 0);
    }
    __syncthreads();
  }

  if constexpr (ALPHA){
    #pragma unroll
    for (int mi = 0; mi < 2; mi++){
      float pu[4] = {0.f,0.f,0.f,0.f}, pv[4] = {0.f,0.f,0.f,0.f};
      int rbase = row0 + wr + mi*16 + (lane >> 4)*4;
      #pragma unroll
      for (int ni = 0; ni < 2; ni++){
        int c = col0 + wc + ni*16 + (lane & 15);
        float bv = BIAS ? bias[c] : 0.f;
        float uc = u2[c], vc = v2[c];
        #pragma unroll
        for (int r = 0; r < 4; r++){
          float v = acc[mi][ni][r] + bv;
          if (RELU) v = fmaxf(v, 0.f);
          if (rbase + r < M)
            ((ushort*)Cout)[(size_t)(rbase+r)*N + c] = f2bf(v);
          pu[r] += v*uc; pv[r] += v*vc;
        }
      }
      #pragma unroll
      for (int off = 8; off; off >>= 1){
        #pragma unroll
        for (int r = 0; r < 4; r++){
          pu[r] += __shfl_xor(pu[r], off);
          pv[r] += __shfl_xor(pv[r], off);
        }
      }
      if ((lane & 15) == 0){
        #pragma unroll
        for (int r = 0; r < 4; r++){
          if (rbase + r < M){
            atomicAdd(&as2[rbase+r], pu[r]);
            atomicAdd(&ad2[rbase+r], pv[r]);
          }
        }
      }
    }
  } else {
    #pragma unroll
    for (int mi = 0; mi < 2; mi++){
      #pragma unroll
      for (int ni = 0; ni < 2; ni++){
        int c = col0 + wc + ni*16 + (lane & 15);
        int rbase = row0 + wr + mi*16 + (lane >> 4)*4;
        float bv = BIAS ? bias[c] : 0.f;
        #pragma unroll
        for (int r = 0; r < 4; r++){
          int row = rbase + r;
          if (row >= M) continue;
          float v = acc[mi][ni][r] + bv;
          if (RELU) v = fmaxf(v, 0.f);
          if (OUTBF16) ((ushort*)Cout)[(size_t)row*N + c] = f2bf(v);
          else         ((float*)Cout)[(size_t)row*N + c] = v;
        }
      }
    }
  }
}

// ---------------- launch ----------------

extern "C" void kernel_launch(void* const* d_in, const int* in_sizes, int n_in,
                              void* d_out, int out_size, void* d_ws, size_t ws_size,
                              hipStream_t stream){
  const float* x   = (const float*)d_in[0];
  const int*   ei  = (const int*)d_in[1];
  const float* W1  = (const float*)d_in[3];
  const float* a1s = (const float*)d_in[4];
  const float* a1d = (const float*)d_in[5];
  const float* b1  = (const float*)d_in[6];
  const float* W2  = (const float*)d_in[7];
  const float* a2s = (const float*)d_in[8];
  const float* a2d = (const float*)d_in[9];
  const float* b2  = (const float*)d_in[10];
  const float* Wm1 = (const float*)d_in[11];
  const float* bm1 = (const float*)d_in[12];
  const float* Wm2 = (const float*)d_in[13];
  const float* bm2 = (const float*)d_in[14];
  float* out = (float*)d_out;

  const int N = NNODES, E = NEDGES;
  const int TOT = E + N;

  char* w = (char*)d_ws;
  auto alloc = [&](size_t bytes)->void*{
    void* p = (void*)w;
    w += (bytes + 255) & ~(size_t)255;
    return p;
  };
  // zero region (written by prep_weights zero blocks): cursor_b | as2 | ad2 = 401408 B
  int*      cursor_b = (int*)alloc(NBUCK*4);            // 1024 B
  float*    as2      = (float*)alloc((size_t)N*4);      // 200192 B padded
  float*    ad2      = (float*)alloc((size_t)N*4);      // 200192 B padded
  unsigned* binned   = (unsigned*)alloc((size_t)NBUCK*CAP*4);
  int*      rowptr   = (int*)alloc((size_t)(N+1)*4);
  int*      csr_src  = (int*)alloc((size_t)TOT*4);
  ushort*   xb       = (ushort*)alloc((size_t)N*64*2);
  ushort*   W1t      = (ushort*)alloc((size_t)64*128*2);
  ushort*   W2t      = (ushort*)alloc((size_t)128*64*2);
  ushort*   Wm1t     = (ushort*)alloc((size_t)64*256*2);
  ushort*   Wm2t     = (ushort*)alloc((size_t)256*256*2);
  float*    u1       = (float*)alloc(128*4);
  float*    v1       = (float*)alloc(128*4);
  float*    u2       = (float*)alloc(128*4);
  float*    v2       = (float*)alloc(128*4);
  float*    as1      = (float*)alloc((size_t)N*4);
  float*    ad1      = (float*)alloc((size_t)N*4);
  ushort*   aggx     = (ushort*)alloc((size_t)N*64*2);
  ushort*   out1b    = (ushort*)alloc((size_t)N*128*2);
  ushort*   h2b      = (ushort*)alloc((size_t)N*64*2);
  ushort*   out2b    = (ushort*)alloc((size_t)N*64*2);
  ushort*   hidb     = (ushort*)alloc((size_t)N*256*2);
  (void)ws_size; (void)n_in; (void)in_sizes; (void)out_size;

  // prep 1: weight transposes | u/v vectors | zero cursor_b/as2/ad2
  prep_weights_kernel<<<PREP_WB + 1 + PREP_ZB, 256, 0, stream>>>(
      W1, W2, Wm1, Wm2, a1s, a1d, a2s, a2d,
      W1t, W2t, Wm1t, Wm2t, u1, v1, u2, v2, (uint4*)cursor_b);

  // CSR pass 1 (binning) merged with x-prep (needs u1/v1 from prep_weights)
  bin_edges_kernel<<<BIN_B + XPREP_B, 256, 0, stream>>>(
      ei, cursor_b, binned, x, u1, v1, xb, as1, ad1, E, N);
  build_csr_kernel<<<NBUCK_USED, 256, 0, stream>>>(binned, cursor_b, csr_src, rowptr, N, TOT);

  const int mb = (N + 63)/64;
  dim3 blk(256);
  const int nwave = (N*64 + 255)/256;

  // GAT layer 1: aggregate x (64ch), then W1 (+b1, relu, as2/ad2 alphas) via GEMM
  aggc64_kernel<false><<<nwave, 256, 0, stream>>>(rowptr, csr_src, xb, as1, ad1, nullptr, aggx, N);
  gemm_bf16_kernel<true,true,true,true><<<dim3(2, mb), blk, 0, stream>>>(
      aggx, W1t, b1, out1b, N, 64, 128, u2, v2, as2, ad2);
  // GAT layer 2: transform then aggregate
  gemm_bf16_kernel<false,false,true,false><<<dim3(1, mb), blk, 0, stream>>>(
      out1b, W2t, nullptr, h2b, N, 128, 64, nullptr, nullptr, nullptr, nullptr);
  aggc64_kernel<true><<<nwave, 256, 0, stream>>>(rowptr, csr_src, h2b, as2, ad2, b2, out2b, N);
  // MLP
  gemm_bf16_kernel<true,true ,true ,false><<<dim3(4, mb), blk, 0, stream>>>(
      out2b, Wm1t, bm1, hidb, N, 64, 256, nullptr, nullptr, nullptr, nullptr);
  gemm_bf16_kernel<true,false,false,false><<<dim3(4, mb), blk, 0, stream>>>(
      hidb, Wm2t, bm2, out, N, 256, 256, nullptr, nullptr, nullptr, nullptr);
}